// Round 2
// baseline (241.142 us; speedup 1.0000x reference)
//
#include <hip/hip_runtime.h>
#include <math.h>

#define N_PTS 16384
#define M_TGT 16384
#define TPN 8192
#define DUB2 4.0f
#define KEYSPACE (4*64*64*64)
#define BMASK_WORDS (KEYSPACE/32)
#define CAP 8192            // per-batch bucket capacity (actual ~4096, +74 sigma margin)
#define SL 512              // target slice size
#define NSL (CAP / SL)      // 16 slices per batch
#define PCHK 512            // points per nn block

__device__ __forceinline__ unsigned int mono_key(float f) {
    unsigned int u = __float_as_uint(f);
    return (u & 0x80000000u) ? ~u : (u | 0x80000000u);
}

// K1: fea_up = relu(fea @ Wup); pred = fea_up @ Wcls
__global__ __launch_bounds__(256) void k_gemm(const float* __restrict__ fea,
        const float* __restrict__ Wup, const float* __restrict__ Wcls,
        float* __restrict__ out_pred, float* __restrict__ out_fea) {
    __shared__ float Ws[64 * 64];
    __shared__ float fs[16 * 68];
    const int tid = threadIdx.x;
    const int r0 = blockIdx.x * 16;

    for (int t = tid; t < 1024; t += 256)
        ((float4*)Ws)[t] = ((const float4*)Wup)[t];
    {
        float4 v = ((const float4*)(fea + r0 * 64))[tid];
        int r = tid >> 4, c = (tid & 15) * 4;
        fs[r*68 + c + 0] = v.x; fs[r*68 + c + 1] = v.y;
        fs[r*68 + c + 2] = v.z; fs[r*68 + c + 3] = v.w;
    }
    __syncthreads();

    const int cg = tid & 15;
    const int r  = tid >> 4;
    float a0 = 0.f, a1 = 0.f, a2 = 0.f, a3 = 0.f;
    const float* fr = fs + r * 68;
    #pragma unroll
    for (int k = 0; k < 64; ++k) {
        float f = fr[k];
        float4 w = *(const float4*)&Ws[k * 64 + cg * 4];
        a0 = fmaf(f, w.x, a0); a1 = fmaf(f, w.y, a1);
        a2 = fmaf(f, w.z, a2); a3 = fmaf(f, w.w, a3);
    }
    a0 = fmaxf(a0, 0.f); a1 = fmaxf(a1, 0.f);
    a2 = fmaxf(a2, 0.f); a3 = fmaxf(a3, 0.f);
    const int row = r0 + r;
    *(float4*)&out_fea[row * 64 + cg * 4] = make_float4(a0, a1, a2, a3);

    float4 wc = *(const float4*)&Wcls[cg * 4];
    float s = a0*wc.x + a1*wc.y + a2*wc.z + a3*wc.w;
    for (int off = 1; off < 16; off <<= 1) s += __shfl_xor(s, off, 16);
    if (cg == 0) out_pred[row] = s;
}

// K2: exact 8192nd-smallest via 4-pass radix-256 select.
// Keys cached in LDS; wave-private histograms; parallel Hillis-Steele scan.
__global__ __launch_bounds__(1024) void k_select(const float* __restrict__ p,
                                                 float* __restrict__ thres_out) {
    __shared__ unsigned int keys[N_PTS];        // 64 KB
    __shared__ unsigned int whist[16][256];     // 16 KB wave-private hists
    __shared__ unsigned int hist[256];
    __shared__ unsigned int scanb[256];
    __shared__ unsigned int sh_prefix, sh_rank;
    const int tid = threadIdx.x;
    const int w = tid >> 6;

    for (int i = tid; i < N_PTS / 4; i += 1024) {
        float4 v = ((const float4*)p)[i];
        keys[i*4 + 0] = mono_key(v.x);
        keys[i*4 + 1] = mono_key(v.y);
        keys[i*4 + 2] = mono_key(v.z);
        keys[i*4 + 3] = mono_key(v.w);
    }
    if (tid == 0) { sh_prefix = 0u; sh_rank = TPN - 1; }
    __syncthreads();

    for (int pass = 0; pass < 4; ++pass) {
        const int shift = 24 - pass * 8;
        const unsigned int prefix = sh_prefix;
        const unsigned int rank = sh_rank;
        for (int t = tid; t < 16 * 256; t += 1024) ((unsigned int*)whist)[t] = 0u;
        __syncthreads();
        for (int i = tid; i < N_PTS; i += 1024) {
            unsigned int u = keys[i];
            bool match = (pass == 0) || ((u >> (shift + 8)) == prefix);
            if (match) atomicAdd(&whist[w][(u >> shift) & 255u], 1u);
        }
        __syncthreads();
        if (tid < 256) {
            unsigned int s = 0u;
            #pragma unroll
            for (int ww = 0; ww < 16; ++ww) s += whist[ww][tid];
            hist[tid] = s;
            scanb[tid] = s;
        }
        __syncthreads();
        for (int d = 1; d < 256; d <<= 1) {
            unsigned int v = 0u;
            if (tid < 256 && tid >= d) v = scanb[tid - d];
            __syncthreads();
            if (tid < 256) scanb[tid] += v;
            __syncthreads();
        }
        if (tid < 256) {
            unsigned int hi = scanb[tid];        // inclusive prefix
            unsigned int lo = hi - hist[tid];    // exclusive
            if (rank >= lo && rank < hi) {
                sh_prefix = (prefix << 8) | (unsigned int)tid;
                sh_rank = rank - lo;
            }
        }
        __syncthreads();
    }
    if (tid == 0) {
        unsigned int u = sh_prefix;
        thres_out[0] = (u & 0x80000000u) ? __uint_as_float(u ^ 0x80000000u)
                                         : __uint_as_float(~u);
    }
}

// K3: fused scatter — targets: bitmask + (-2x,-2y,-2z,tt) into per-batch region;
//     points: (x,y,z,pp) + orig idx into per-batch region. cnt[0..3]=targets, cnt[4..7]=points.
__global__ __launch_bounds__(256) void k_scatter(const int* __restrict__ tc,
        const int* __restrict__ pc_, unsigned int* __restrict__ bmask,
        int* __restrict__ cnt, float4* __restrict__ tgt4,
        float4* __restrict__ pt4, int* __restrict__ porig) {
    int id = blockIdx.x * 256 + threadIdx.x;
    if (id < M_TGT) {
        int4 c = *(const int4*)&tc[id * 4];
        int key = ((c.x * 64 + c.y) * 64 + c.z) * 64 + c.w;
        atomicOr(&bmask[key >> 5], 1u << (key & 31));
        float x = (float)c.y, y = (float)c.z, z = (float)c.w;
        int r = atomicAdd(&cnt[c.x], 1);
        if (r < CAP) tgt4[c.x * CAP + r] = make_float4(-2.f*x, -2.f*y, -2.f*z, x*x + y*y + z*z);
    } else {
        id -= M_TGT;
        int4 c = *(const int4*)&pc_[id * 4];
        float x = (float)c.y, y = (float)c.z, z = (float)c.w;
        int r = atomicAdd(&cnt[4 + c.x], 1);
        if (r < CAP) {
            pt4[c.x * CAP + r] = make_float4(x, y, z, x*x + y*y + z*z);
            porig[c.x * CAP + r] = id;
        }
    }
}

// K4: same-batch NN. block = (batch b, point-chunk c, target-slice s).
// Stages SL targets in LDS; 2 points/thread in registers; 4 VALU ops/pair.
// partial[orig*NSL + s] = min_j (tt - 2 p.t)   (pp added in k_final)
__global__ __launch_bounds__(256) void k_nn(const float4* __restrict__ tgt4,
        const float4* __restrict__ pt4, const int* __restrict__ porig,
        const int* __restrict__ cnt, float* __restrict__ partial) {
    __shared__ float4 tg[SL];
    const int tid = threadIdx.x;
    const int s = blockIdx.x & (NSL - 1);
    const int pchunk = blockIdx.x >> 4;            // 0..63
    const int b = pchunk >> 4;                     // 0..3
    const int c = pchunk & 15;
    const int cntt = min(cnt[b], CAP);
    const int cntp = min(cnt[4 + b], CAP);
    if (c * PCHK >= cntp || s * SL >= cntt) return;

    const int lim = cntt - s * SL;
    const float4* tb = tgt4 + b * CAP + s * SL;
    for (int k = tid; k < SL; k += 256)
        tg[k] = (k < lim) ? tb[k] : make_float4(0.f, 0.f, 0.f, 3.4e38f);
    __syncthreads();

    const int p0 = c * PCHK;
    const int pidx0 = p0 + tid, pidx1 = p0 + 256 + tid;
    float4 P0 = pt4[b * CAP + pidx0];
    float4 P1 = pt4[b * CAP + pidx1];
    float m0 = 3.4e38f, m1 = 3.4e38f;
    #pragma unroll 4
    for (int j = 0; j < SL; ++j) {
        float4 mm = tg[j];
        float d0 = fmaf(P0.x, mm.x, mm.w);
        d0 = fmaf(P0.y, mm.y, d0);
        d0 = fmaf(P0.z, mm.z, d0);
        m0 = fminf(m0, d0);
        float d1 = fmaf(P1.x, mm.x, mm.w);
        d1 = fmaf(P1.y, mm.y, d1);
        d1 = fmaf(P1.z, mm.z, d1);
        m1 = fminf(m1, d1);
    }
    if (pidx0 < cntp) partial[porig[b * CAP + pidx0] * NSL + s] = m0;
    if (pidx1 < cntp) partial[porig[b * CAP + pidx1] * NSL + s] = m1;
}

// K5: epilogue — keep/keep_target/loss + scale fea_pruned in place. 64 rows/block.
__global__ __launch_bounds__(256) void k_final(const int* __restrict__ coords,
        const unsigned int* __restrict__ bmask, const float* __restrict__ thres_p,
        const float* __restrict__ partial, const int* __restrict__ cnt,
        const float* __restrict__ out_pred, float* __restrict__ out_fea,
        float* __restrict__ out_keep, float* __restrict__ out_kt,
        float* __restrict__ out_loss) {
    __shared__ float kscale[64];
    const int tid = threadIdx.x;
    const int r0 = blockIdx.x * 64;
    if (tid < 64) {
        const int i = r0 + tid;
        float p = out_pred[i];
        float thres = thres_p[0];
        int4 c = *(const int4*)&coords[i * 4];
        const int b = c.x;
        const int cntt = min(cnt[b], CAP);
        const int ns = (cntt + SL - 1) >> 9;
        float dmin = 3.4e38f;
        for (int s = 0; s < ns; ++s) dmin = fminf(dmin, partial[i * NSL + s]);
        float px = (float)c.y, py = (float)c.z, pz = (float)c.w;
        float pp = px*px + py*py + pz*pz;
        float dists = fmaxf(dmin + pp, 0.f);
        int key = ((c.x * 64 + c.y) * 64 + c.z) * 64 + c.w;
        bool kt = (bmask[key >> 5] >> (key & 31)) & 1u;
        bool keep0 = (p <= thres);
        bool pm = (p > DUB2), tm = (dists > DUB2);
        float loss = (pm && tm) ? p : ((!pm && tm) ? DUB2 : dists);
        bool kf = keep0 || kt;
        out_keep[i] = kf ? 1.f : 0.f;
        out_kt[i]  = kt ? 1.f : 0.f;
        out_loss[i] = loss;
        kscale[tid] = kf ? 1.f : 0.f;
    }
    __syncthreads();
    float4* fbase = (float4*)(out_fea + r0 * 64);
    #pragma unroll
    for (int q = 0; q < 4; ++q) {
        int v = tid + q * 256;
        float sc = kscale[v >> 4];
        float4 x = fbase[v];
        x.x *= sc; x.y *= sc; x.z *= sc; x.w *= sc;
        fbase[v] = x;
    }
}

extern "C" void kernel_launch(void* const* d_in, const int* in_sizes, int n_in,
                              void* d_out, int out_size, void* d_ws, size_t ws_size,
                              hipStream_t stream) {
    const float* fea     = (const float*)d_in[0];
    const float* Wup     = (const float*)d_in[1];
    const float* Wcls    = (const float*)d_in[2];
    const int*   coords  = (const int*)d_in[3];
    const int*   tcoords = (const int*)d_in[4];

    float* out      = (float*)d_out;
    float* out_pred = out;
    float* out_fea  = out + N_PTS;
    float* out_keep = out + N_PTS + N_PTS * 64;
    float* out_kt   = out_keep + N_PTS;
    float* out_loss = out_kt + N_PTS;

    char* ws = (char*)d_ws;
    int*          cnt     = (int*)ws;                          // 64 B (cnt[0..3]=tgt, [4..7]=pts)
    unsigned int* bmask   = (unsigned int*)(ws + 64);          // 128 KB -> ends 131136
    float*        thres   = (float*)(ws + 131136);             // 256 B  -> 131392
    float4*       tgt4    = (float4*)(ws + 131392);            // 512 KB -> 655680
    float4*       pt4     = (float4*)(ws + 655680);            // 512 KB -> 1179968
    int*          porig   = (int*)(ws + 1179968);              // 128 KB -> 1311040
    float*        partial = (float*)(ws + 1311040);            // 1 MB   -> 2359616

    hipMemsetAsync(ws, 0, 64 + BMASK_WORDS * sizeof(unsigned int), stream);
    k_gemm   <<<N_PTS / 16, 256, 0, stream>>>(fea, Wup, Wcls, out_pred, out_fea);
    k_scatter<<<(M_TGT + N_PTS) / 256, 256, 0, stream>>>(tcoords, coords, bmask, cnt,
                                                          tgt4, pt4, porig);
    k_select <<<1, 1024, 0, stream>>>(out_pred, thres);
    k_nn     <<<(4 * NSL) * NSL, 256, 0, stream>>>(tgt4, pt4, porig, cnt, partial);
    k_final  <<<N_PTS / 64, 256, 0, stream>>>(coords, bmask, thres, partial, cnt,
                                              out_pred, out_fea, out_keep, out_kt, out_loss);
}

// Round 4
// 86.653 us; speedup vs baseline: 2.7828x; 2.7828x over previous
//
#include <hip/hip_runtime.h>
#include <math.h>

#define N_PTS 16384
#define M_TGT 16384
#define TPN 8192
#define DUB2 4.0f
#define KEYSPACE (4*64*64*64)
#define BMASK_WORDS (KEYSPACE/32)
#define CAP 8192            // per-batch bucket capacity (actual ~4096, +74 sigma margin)
#define SL 512              // target slice size
#define NSL (CAP / SL)      // 16 slices per batch
#define PCHK 512            // points per nn block

__device__ __forceinline__ unsigned int mono_key(float f) {
    unsigned int u = __float_as_uint(f);
    return (u & 0x80000000u) ? ~u : (u | 0x80000000u);
}

// K1: fea_up = relu(fea @ Wup); pred = fea_up @ Wcls
__global__ __launch_bounds__(256) void k_gemm(const float* __restrict__ fea,
        const float* __restrict__ Wup, const float* __restrict__ Wcls,
        float* __restrict__ out_pred, float* __restrict__ out_fea) {
    __shared__ float Ws[64 * 64];
    __shared__ float fs[16 * 68];
    const int tid = threadIdx.x;
    const int r0 = blockIdx.x * 16;

    for (int t = tid; t < 1024; t += 256)
        ((float4*)Ws)[t] = ((const float4*)Wup)[t];
    {
        float4 v = ((const float4*)(fea + r0 * 64))[tid];
        int r = tid >> 4, c = (tid & 15) * 4;
        fs[r*68 + c + 0] = v.x; fs[r*68 + c + 1] = v.y;
        fs[r*68 + c + 2] = v.z; fs[r*68 + c + 3] = v.w;
    }
    __syncthreads();

    const int cg = tid & 15;
    const int r  = tid >> 4;
    float a0 = 0.f, a1 = 0.f, a2 = 0.f, a3 = 0.f;
    const float* fr = fs + r * 68;
    #pragma unroll
    for (int k = 0; k < 64; ++k) {
        float f = fr[k];
        float4 w = *(const float4*)&Ws[k * 64 + cg * 4];
        a0 = fmaf(f, w.x, a0); a1 = fmaf(f, w.y, a1);
        a2 = fmaf(f, w.z, a2); a3 = fmaf(f, w.w, a3);
    }
    a0 = fmaxf(a0, 0.f); a1 = fmaxf(a1, 0.f);
    a2 = fmaxf(a2, 0.f); a3 = fmaxf(a3, 0.f);
    const int row = r0 + r;
    *(float4*)&out_fea[row * 64 + cg * 4] = make_float4(a0, a1, a2, a3);

    float4 wc = *(const float4*)&Wcls[cg * 4];
    float s = a0*wc.x + a1*wc.y + a2*wc.z + a3*wc.w;
    for (int off = 1; off < 16; off <<= 1) s += __shfl_xor(s, off, 16);
    if (cg == 0) out_pred[row] = s;
}

// K2: exact 8192nd-smallest via 4-pass radix-256 select.
// Keys cached in LDS; wave-private histograms; parallel Hillis-Steele scan.
__global__ __launch_bounds__(1024) void k_select(const float* __restrict__ p,
                                                 float* __restrict__ thres_out) {
    __shared__ unsigned int keys[N_PTS];        // 64 KB
    __shared__ unsigned int whist[16][256];     // 16 KB wave-private hists
    __shared__ unsigned int hist[256];
    __shared__ unsigned int scanb[256];
    __shared__ unsigned int sh_prefix, sh_rank;
    const int tid = threadIdx.x;
    const int w = tid >> 6;

    for (int i = tid; i < N_PTS / 4; i += 1024) {
        float4 v = ((const float4*)p)[i];
        keys[i*4 + 0] = mono_key(v.x);
        keys[i*4 + 1] = mono_key(v.y);
        keys[i*4 + 2] = mono_key(v.z);
        keys[i*4 + 3] = mono_key(v.w);
    }
    if (tid == 0) { sh_prefix = 0u; sh_rank = TPN - 1; }
    __syncthreads();

    for (int pass = 0; pass < 4; ++pass) {
        const int shift = 24 - pass * 8;
        const unsigned int prefix = sh_prefix;
        const unsigned int rank = sh_rank;
        for (int t = tid; t < 16 * 256; t += 1024) ((unsigned int*)whist)[t] = 0u;
        __syncthreads();
        for (int i = tid; i < N_PTS; i += 1024) {
            unsigned int u = keys[i];
            bool match = (pass == 0) || ((u >> (shift + 8)) == prefix);
            if (match) atomicAdd(&whist[w][(u >> shift) & 255u], 1u);
        }
        __syncthreads();
        if (tid < 256) {
            unsigned int s = 0u;
            #pragma unroll
            for (int ww = 0; ww < 16; ++ww) s += whist[ww][tid];
            hist[tid] = s;
            scanb[tid] = s;
        }
        __syncthreads();
        for (int d = 1; d < 256; d <<= 1) {
            unsigned int v = 0u;
            if (tid < 256 && tid >= d) v = scanb[tid - d];
            __syncthreads();
            if (tid < 256) scanb[tid] += v;
            __syncthreads();
        }
        if (tid < 256) {
            unsigned int hi = scanb[tid];        // inclusive prefix
            unsigned int lo = hi - hist[tid];    // exclusive
            if (rank >= lo && rank < hi) {
                sh_prefix = (prefix << 8) | (unsigned int)tid;
                sh_rank = rank - lo;
            }
        }
        __syncthreads();
    }
    if (tid == 0) {
        unsigned int u = sh_prefix;
        thres_out[0] = (u & 0x80000000u) ? __uint_as_float(u ^ 0x80000000u)
                                         : __uint_as_float(~u);
    }
}

// K3: fused scatter with WAVE-AGGREGATED atomics (4 atomics/wave, not 64).
// Targets: bitmask + (-2x,-2y,-2z,tt) into per-batch region;
// points: (x,y,z,pp) + orig idx. cnt[0..3]=targets, cnt[4..7]=points.
__global__ __launch_bounds__(256) void k_scatter(const int* __restrict__ tc,
        const int* __restrict__ pc_, unsigned int* __restrict__ bmask,
        int* __restrict__ cnt, float4* __restrict__ tgt4,
        float4* __restrict__ pt4, int* __restrict__ porig) {
    const int id = blockIdx.x * 256 + threadIdx.x;
    const int lane = threadIdx.x & 63;
    const unsigned long long below = (lane == 63) ? ~0ull >> 1
                                   : ((1ull << lane) - 1ull);
    const bool is_tgt = (id < M_TGT);          // block-uniform (M_TGT % 256 == 0)
    const int idx = is_tgt ? id : id - M_TGT;
    int4 c = is_tgt ? *(const int4*)&tc[idx * 4] : *(const int4*)&pc_[idx * 4];
    const int b = c.x;
    float x = (float)c.y, y = (float)c.z, z = (float)c.w;
    float ss = x*x + y*y + z*z;

    if (is_tgt) {
        int key = ((c.x * 64 + c.y) * 64 + c.z) * 64 + c.w;
        atomicOr(&bmask[key >> 5], 1u << (key & 31));
    }
    const int cbase = is_tgt ? 0 : 4;
    #pragma unroll
    for (int bb = 0; bb < 4; ++bb) {
        unsigned long long m = __ballot(b == bb);
        if (m == 0ull) continue;               // wave-uniform
        int leader = __ffsll((unsigned long long)m) - 1;
        int base = 0;
        if (lane == leader) base = atomicAdd(&cnt[cbase + bb], __popcll(m));
        base = __shfl(base, leader);
        if (b == bb) {
            int r = base + __popcll(m & below);
            if (r < CAP) {
                if (is_tgt) {
                    tgt4[b * CAP + r] = make_float4(-2.f*x, -2.f*y, -2.f*z, ss);
                } else {
                    pt4[b * CAP + r] = make_float4(x, y, z, ss);
                    porig[b * CAP + r] = idx;
                }
            }
        }
    }
}

// K4: same-batch NN. block = (batch b, point-chunk c, target-slice s).
// Stages SL targets in LDS; 2 points/thread in registers; 4 VALU ops/pair.
// partial[orig*NSL + s] = min_j (tt - 2 p.t)   (pp added in k_final)
__global__ __launch_bounds__(256) void k_nn(const float4* __restrict__ tgt4,
        const float4* __restrict__ pt4, const int* __restrict__ porig,
        const int* __restrict__ cnt, float* __restrict__ partial) {
    __shared__ float4 tg[SL];
    const int tid = threadIdx.x;
    const int s = blockIdx.x & (NSL - 1);
    const int pchunk = blockIdx.x >> 4;            // 0..63
    const int b = pchunk >> 4;                     // 0..3
    const int c = pchunk & 15;
    const int cntt = min(cnt[b], CAP);
    const int cntp = min(cnt[4 + b], CAP);
    if (c * PCHK >= cntp || s * SL >= cntt) return;

    const int lim = cntt - s * SL;
    const float4* tb = tgt4 + b * CAP + s * SL;
    for (int k = tid; k < SL; k += 256)
        tg[k] = (k < lim) ? tb[k] : make_float4(0.f, 0.f, 0.f, 3.4e38f);
    __syncthreads();

    const int p0 = c * PCHK;
    const int pidx0 = p0 + tid, pidx1 = p0 + 256 + tid;
    float4 P0 = pt4[b * CAP + pidx0];
    float4 P1 = pt4[b * CAP + pidx1];
    float m0 = 3.4e38f, m1 = 3.4e38f;
    #pragma unroll 4
    for (int j = 0; j < SL; ++j) {
        float4 mm = tg[j];
        float d0 = fmaf(P0.x, mm.x, mm.w);
        d0 = fmaf(P0.y, mm.y, d0);
        d0 = fmaf(P0.z, mm.z, d0);
        m0 = fminf(m0, d0);
        float d1 = fmaf(P1.x, mm.x, mm.w);
        d1 = fmaf(P1.y, mm.y, d1);
        d1 = fmaf(P1.z, mm.z, d1);
        m1 = fminf(m1, d1);
    }
    if (pidx0 < cntp) partial[porig[b * CAP + pidx0] * NSL + s] = m0;
    if (pidx1 < cntp) partial[porig[b * CAP + pidx1] * NSL + s] = m1;
}

// K5: epilogue — keep/keep_target/loss + scale fea_pruned in place. 64 rows/block.
__global__ __launch_bounds__(256) void k_final(const int* __restrict__ coords,
        const unsigned int* __restrict__ bmask, const float* __restrict__ thres_p,
        const float* __restrict__ partial, const int* __restrict__ cnt,
        const float* __restrict__ out_pred, float* __restrict__ out_fea,
        float* __restrict__ out_keep, float* __restrict__ out_kt,
        float* __restrict__ out_loss) {
    __shared__ float kscale[64];
    const int tid = threadIdx.x;
    const int r0 = blockIdx.x * 64;
    if (tid < 64) {
        const int i = r0 + tid;
        float p = out_pred[i];
        float thres = thres_p[0];
        int4 c = *(const int4*)&coords[i * 4];
        const int b = c.x;
        const int cntt = min(cnt[b], CAP);
        const int ns = (cntt + SL - 1) >> 9;
        float dmin = 3.4e38f;
        for (int s = 0; s < ns; ++s) dmin = fminf(dmin, partial[i * NSL + s]);
        float px = (float)c.y, py = (float)c.z, pz = (float)c.w;
        float pp = px*px + py*py + pz*pz;
        float dists = fmaxf(dmin + pp, 0.f);
        int key = ((c.x * 64 + c.y) * 64 + c.z) * 64 + c.w;
        bool kt = (bmask[key >> 5] >> (key & 31)) & 1u;
        bool keep0 = (p <= thres);
        bool pm = (p > DUB2), tm = (dists > DUB2);
        float loss = (pm && tm) ? p : ((!pm && tm) ? DUB2 : dists);
        bool kf = keep0 || kt;
        out_keep[i] = kf ? 1.f : 0.f;
        out_kt[i]  = kt ? 1.f : 0.f;
        out_loss[i] = loss;
        kscale[tid] = kf ? 1.f : 0.f;
    }
    __syncthreads();
    float4* fbase = (float4*)(out_fea + r0 * 64);
    #pragma unroll
    for (int q = 0; q < 4; ++q) {
        int v = tid + q * 256;
        float sc = kscale[v >> 4];
        float4 x = fbase[v];
        x.x *= sc; x.y *= sc; x.z *= sc; x.w *= sc;
        fbase[v] = x;
    }
}

extern "C" void kernel_launch(void* const* d_in, const int* in_sizes, int n_in,
                              void* d_out, int out_size, void* d_ws, size_t ws_size,
                              hipStream_t stream) {
    const float* fea     = (const float*)d_in[0];
    const float* Wup     = (const float*)d_in[1];
    const float* Wcls    = (const float*)d_in[2];
    const int*   coords  = (const int*)d_in[3];
    const int*   tcoords = (const int*)d_in[4];

    float* out      = (float*)d_out;
    float* out_pred = out;
    float* out_fea  = out + N_PTS;
    float* out_keep = out + N_PTS + N_PTS * 64;
    float* out_kt   = out_keep + N_PTS;
    float* out_loss = out_kt + N_PTS;

    char* ws = (char*)d_ws;
    int*          cnt     = (int*)ws;                          // 64 B (cnt[0..3]=tgt, [4..7]=pts)
    unsigned int* bmask   = (unsigned int*)(ws + 64);          // 128 KB -> ends 131136
    float*        thres   = (float*)(ws + 131136);             // 256 B  -> 131392
    float4*       tgt4    = (float4*)(ws + 131392);            // 512 KB -> 655680
    float4*       pt4     = (float4*)(ws + 655680);            // 512 KB -> 1179968
    int*          porig   = (int*)(ws + 1179968);              // 128 KB -> 1311040
    float*        partial = (float*)(ws + 1311040);            // 1 MB   -> 2359616

    hipMemsetAsync(ws, 0, 64 + BMASK_WORDS * sizeof(unsigned int), stream);
    k_gemm   <<<N_PTS / 16, 256, 0, stream>>>(fea, Wup, Wcls, out_pred, out_fea);
    k_scatter<<<(M_TGT + N_PTS) / 256, 256, 0, stream>>>(tcoords, coords, bmask, cnt,
                                                          tgt4, pt4, porig);
    k_select <<<1, 1024, 0, stream>>>(out_pred, thres);
    k_nn     <<<(4 * NSL) * NSL, 256, 0, stream>>>(tgt4, pt4, porig, cnt, partial);
    k_final  <<<N_PTS / 64, 256, 0, stream>>>(coords, bmask, thres, partial, cnt,
                                              out_pred, out_fea, out_keep, out_kt, out_loss);
}

// Round 9
// 82.010 us; speedup vs baseline: 2.9404x; 1.0566x over previous
//
#include <hip/hip_runtime.h>
#include <math.h>

#define N_PTS 16384
#define M_TGT 16384
#define TPN 8192
#define DUB2 4.0f
#define KEYSPACE (4*64*64*64)
#define BMASK_WORDS (KEYSPACE/32)
#define CAP 8192            // per-batch bucket capacity (actual ~4096, +74 sigma margin)
#define SL 512              // target slice size
#define NSL (CAP / SL)      // 16 slices per batch
#define PCHK 512            // points per nn block

__device__ __forceinline__ unsigned int mono_key(float f) {
    unsigned int u = __float_as_uint(f);
    return (u & 0x80000000u) ? ~u : (u | 0x80000000u);
}

// K1: fea_up = relu(fea @ Wup); pred = fea_up @ Wcls
// Also zeroes bmask (32 words/block) + cnt (block 0) — replaces the pathologically
// slow runtime hipMemsetAsync fill (39.6 us for 128 KB); stream order guarantees
// completion before k_scatter's atomics.
__global__ __launch_bounds__(256) void k_gemm(const float* __restrict__ fea,
        const float* __restrict__ Wup, const float* __restrict__ Wcls,
        float* __restrict__ out_pred, float* __restrict__ out_fea,
        unsigned int* __restrict__ bmask, int* __restrict__ cnt) {
    __shared__ float Ws[64 * 64];
    __shared__ float fs[16 * 68];
    const int tid = threadIdx.x;
    const int r0 = blockIdx.x * 16;

    if (tid < 32) bmask[blockIdx.x * 32 + tid] = 0u;          // 1024 blocks x 32 = 32768 words
    else if (blockIdx.x == 0 && tid < 40) cnt[tid - 32] = 0;

    for (int t = tid; t < 1024; t += 256)
        ((float4*)Ws)[t] = ((const float4*)Wup)[t];
    {
        float4 v = ((const float4*)(fea + r0 * 64))[tid];
        int r = tid >> 4, c = (tid & 15) * 4;
        fs[r*68 + c + 0] = v.x; fs[r*68 + c + 1] = v.y;
        fs[r*68 + c + 2] = v.z; fs[r*68 + c + 3] = v.w;
    }
    __syncthreads();

    const int cg = tid & 15;
    const int r  = tid >> 4;
    float a0 = 0.f, a1 = 0.f, a2 = 0.f, a3 = 0.f;
    const float* fr = fs + r * 68;
    #pragma unroll
    for (int k = 0; k < 64; ++k) {
        float f = fr[k];
        float4 w = *(const float4*)&Ws[k * 64 + cg * 4];
        a0 = fmaf(f, w.x, a0); a1 = fmaf(f, w.y, a1);
        a2 = fmaf(f, w.z, a2); a3 = fmaf(f, w.w, a3);
    }
    a0 = fmaxf(a0, 0.f); a1 = fmaxf(a1, 0.f);
    a2 = fmaxf(a2, 0.f); a3 = fmaxf(a3, 0.f);
    const int row = r0 + r;
    *(float4*)&out_fea[row * 64 + cg * 4] = make_float4(a0, a1, a2, a3);

    float4 wc = *(const float4*)&Wcls[cg * 4];
    float s = a0*wc.x + a1*wc.y + a2*wc.z + a3*wc.w;
    for (int off = 1; off < 16; off <<= 1) s += __shfl_xor(s, off, 16);
    if (cg == 0) out_pred[row] = s;
}

// K2: exact 8192nd-smallest via 4-pass radix-256 select.
// Keys cached in LDS; wave-private histograms; parallel Hillis-Steele scan.
__global__ __launch_bounds__(1024) void k_select(const float* __restrict__ p,
                                                 float* __restrict__ thres_out) {
    __shared__ unsigned int keys[N_PTS];        // 64 KB
    __shared__ unsigned int whist[16][256];     // 16 KB wave-private hists
    __shared__ unsigned int hist[256];
    __shared__ unsigned int scanb[256];
    __shared__ unsigned int sh_prefix, sh_rank;
    const int tid = threadIdx.x;
    const int w = tid >> 6;

    for (int i = tid; i < N_PTS / 4; i += 1024) {
        float4 v = ((const float4*)p)[i];
        keys[i*4 + 0] = mono_key(v.x);
        keys[i*4 + 1] = mono_key(v.y);
        keys[i*4 + 2] = mono_key(v.z);
        keys[i*4 + 3] = mono_key(v.w);
    }
    if (tid == 0) { sh_prefix = 0u; sh_rank = TPN - 1; }
    __syncthreads();

    for (int pass = 0; pass < 4; ++pass) {
        const int shift = 24 - pass * 8;
        const unsigned int prefix = sh_prefix;
        const unsigned int rank = sh_rank;
        for (int t = tid; t < 16 * 256; t += 1024) ((unsigned int*)whist)[t] = 0u;
        __syncthreads();
        for (int i = tid; i < N_PTS; i += 1024) {
            unsigned int u = keys[i];
            bool match = (pass == 0) || ((u >> (shift + 8)) == prefix);
            if (match) atomicAdd(&whist[w][(u >> shift) & 255u], 1u);
        }
        __syncthreads();
        if (tid < 256) {
            unsigned int s = 0u;
            #pragma unroll
            for (int ww = 0; ww < 16; ++ww) s += whist[ww][tid];
            hist[tid] = s;
            scanb[tid] = s;
        }
        __syncthreads();
        for (int d = 1; d < 256; d <<= 1) {
            unsigned int v = 0u;
            if (tid < 256 && tid >= d) v = scanb[tid - d];
            __syncthreads();
            if (tid < 256) scanb[tid] += v;
            __syncthreads();
        }
        if (tid < 256) {
            unsigned int hi = scanb[tid];        // inclusive prefix
            unsigned int lo = hi - hist[tid];    // exclusive
            if (rank >= lo && rank < hi) {
                sh_prefix = (prefix << 8) | (unsigned int)tid;
                sh_rank = rank - lo;
            }
        }
        __syncthreads();
    }
    if (tid == 0) {
        unsigned int u = sh_prefix;
        thres_out[0] = (u & 0x80000000u) ? __uint_as_float(u ^ 0x80000000u)
                                         : __uint_as_float(~u);
    }
}

// K3: fused scatter with WAVE-AGGREGATED atomics (4 atomics/wave, not 64).
// Targets: bitmask + (-2x,-2y,-2z,tt) into per-batch region;
// points: (x,y,z,pp) + orig idx. cnt[0..3]=targets, cnt[4..7]=points.
__global__ __launch_bounds__(256) void k_scatter(const int* __restrict__ tc,
        const int* __restrict__ pc_, unsigned int* __restrict__ bmask,
        int* __restrict__ cnt, float4* __restrict__ tgt4,
        float4* __restrict__ pt4, int* __restrict__ porig) {
    const int id = blockIdx.x * 256 + threadIdx.x;
    const int lane = threadIdx.x & 63;
    const unsigned long long below = (lane == 63) ? ~0ull >> 1
                                   : ((1ull << lane) - 1ull);
    const bool is_tgt = (id < M_TGT);          // block-uniform (M_TGT % 256 == 0)
    const int idx = is_tgt ? id : id - M_TGT;
    int4 c = is_tgt ? *(const int4*)&tc[idx * 4] : *(const int4*)&pc_[idx * 4];
    const int b = c.x;
    float x = (float)c.y, y = (float)c.z, z = (float)c.w;
    float ss = x*x + y*y + z*z;

    if (is_tgt) {
        int key = ((c.x * 64 + c.y) * 64 + c.z) * 64 + c.w;
        atomicOr(&bmask[key >> 5], 1u << (key & 31));
    }
    const int cbase = is_tgt ? 0 : 4;
    #pragma unroll
    for (int bb = 0; bb < 4; ++bb) {
        unsigned long long m = __ballot(b == bb);
        if (m == 0ull) continue;               // wave-uniform
        int leader = __ffsll((unsigned long long)m) - 1;
        int base = 0;
        if (lane == leader) base = atomicAdd(&cnt[cbase + bb], __popcll(m));
        base = __shfl(base, leader);
        if (b == bb) {
            int r = base + __popcll(m & below);
            if (r < CAP) {
                if (is_tgt) {
                    tgt4[b * CAP + r] = make_float4(-2.f*x, -2.f*y, -2.f*z, ss);
                } else {
                    pt4[b * CAP + r] = make_float4(x, y, z, ss);
                    porig[b * CAP + r] = idx;
                }
            }
        }
    }
}

// K4: same-batch NN. block = (batch b, point-chunk c, target-slice s).
// Stages SL targets in LDS; 2 points/thread in registers; 4 VALU ops/pair.
// partial[orig*NSL + s] = min_j (tt - 2 p.t)   (pp added in k_final)
__global__ __launch_bounds__(256) void k_nn(const float4* __restrict__ tgt4,
        const float4* __restrict__ pt4, const int* __restrict__ porig,
        const int* __restrict__ cnt, float* __restrict__ partial) {
    __shared__ float4 tg[SL];
    const int tid = threadIdx.x;
    const int s = blockIdx.x & (NSL - 1);
    const int pchunk = blockIdx.x >> 4;            // 0..63
    const int b = pchunk >> 4;                     // 0..3
    const int c = pchunk & 15;
    const int cntt = min(cnt[b], CAP);
    const int cntp = min(cnt[4 + b], CAP);
    if (c * PCHK >= cntp || s * SL >= cntt) return;

    const int lim = cntt - s * SL;
    const float4* tb = tgt4 + b * CAP + s * SL;
    for (int k = tid; k < SL; k += 256)
        tg[k] = (k < lim) ? tb[k] : make_float4(0.f, 0.f, 0.f, 3.4e38f);
    __syncthreads();

    const int p0 = c * PCHK;
    const int pidx0 = p0 + tid, pidx1 = p0 + 256 + tid;
    float4 P0 = pt4[b * CAP + pidx0];
    float4 P1 = pt4[b * CAP + pidx1];
    float m0 = 3.4e38f, m1 = 3.4e38f;
    #pragma unroll 4
    for (int j = 0; j < SL; ++j) {
        float4 mm = tg[j];
        float d0 = fmaf(P0.x, mm.x, mm.w);
        d0 = fmaf(P0.y, mm.y, d0);
        d0 = fmaf(P0.z, mm.z, d0);
        m0 = fminf(m0, d0);
        float d1 = fmaf(P1.x, mm.x, mm.w);
        d1 = fmaf(P1.y, mm.y, d1);
        d1 = fmaf(P1.z, mm.z, d1);
        m1 = fminf(m1, d1);
    }
    if (pidx0 < cntp) partial[porig[b * CAP + pidx0] * NSL + s] = m0;
    if (pidx1 < cntp) partial[porig[b * CAP + pidx1] * NSL + s] = m1;
}

// K5: epilogue — keep/keep_target/loss + scale fea_pruned in place. 64 rows/block.
__global__ __launch_bounds__(256) void k_final(const int* __restrict__ coords,
        const unsigned int* __restrict__ bmask, const float* __restrict__ thres_p,
        const float* __restrict__ partial, const int* __restrict__ cnt,
        const float* __restrict__ out_pred, float* __restrict__ out_fea,
        float* __restrict__ out_keep, float* __restrict__ out_kt,
        float* __restrict__ out_loss) {
    __shared__ float kscale[64];
    const int tid = threadIdx.x;
    const int r0 = blockIdx.x * 64;
    if (tid < 64) {
        const int i = r0 + tid;
        float p = out_pred[i];
        float thres = thres_p[0];
        int4 c = *(const int4*)&coords[i * 4];
        const int b = c.x;
        const int cntt = min(cnt[b], CAP);
        const int ns = (cntt + SL - 1) >> 9;
        float dmin = 3.4e38f;
        for (int s = 0; s < ns; ++s) dmin = fminf(dmin, partial[i * NSL + s]);
        float px = (float)c.y, py = (float)c.z, pz = (float)c.w;
        float pp = px*px + py*py + pz*pz;
        float dists = fmaxf(dmin + pp, 0.f);
        int key = ((c.x * 64 + c.y) * 64 + c.z) * 64 + c.w;
        bool kt = (bmask[key >> 5] >> (key & 31)) & 1u;
        bool keep0 = (p <= thres);
        bool pm = (p > DUB2), tm = (dists > DUB2);
        float loss = (pm && tm) ? p : ((!pm && tm) ? DUB2 : dists);
        bool kf = keep0 || kt;
        out_keep[i] = kf ? 1.f : 0.f;
        out_kt[i]  = kt ? 1.f : 0.f;
        out_loss[i] = loss;
        kscale[tid] = kf ? 1.f : 0.f;
    }
    __syncthreads();
    float4* fbase = (float4*)(out_fea + r0 * 64);
    #pragma unroll
    for (int q = 0; q < 4; ++q) {
        int v = tid + q * 256;
        float sc = kscale[v >> 4];
        float4 x = fbase[v];
        x.x *= sc; x.y *= sc; x.z *= sc; x.w *= sc;
        fbase[v] = x;
    }
}

extern "C" void kernel_launch(void* const* d_in, const int* in_sizes, int n_in,
                              void* d_out, int out_size, void* d_ws, size_t ws_size,
                              hipStream_t stream) {
    const float* fea     = (const float*)d_in[0];
    const float* Wup     = (const float*)d_in[1];
    const float* Wcls    = (const float*)d_in[2];
    const int*   coords  = (const int*)d_in[3];
    const int*   tcoords = (const int*)d_in[4];

    float* out      = (float*)d_out;
    float* out_pred = out;
    float* out_fea  = out + N_PTS;
    float* out_keep = out + N_PTS + N_PTS * 64;
    float* out_kt   = out_keep + N_PTS;
    float* out_loss = out_kt + N_PTS;

    char* ws = (char*)d_ws;
    int*          cnt     = (int*)ws;                          // 64 B (cnt[0..3]=tgt, [4..7]=pts)
    unsigned int* bmask   = (unsigned int*)(ws + 64);          // 128 KB -> ends 131136
    float*        thres   = (float*)(ws + 131136);             // 256 B  -> 131392
    float4*       tgt4    = (float4*)(ws + 131392);            // 512 KB -> 655680
    float4*       pt4     = (float4*)(ws + 655680);            // 512 KB -> 1179968
    int*          porig   = (int*)(ws + 1179968);              // 128 KB -> 1311040
    float*        partial = (float*)(ws + 1311040);            // 1 MB   -> 2359616

    k_gemm   <<<N_PTS / 16, 256, 0, stream>>>(fea, Wup, Wcls, out_pred, out_fea,
                                              bmask, cnt);
    k_scatter<<<(M_TGT + N_PTS) / 256, 256, 0, stream>>>(tcoords, coords, bmask, cnt,
                                                          tgt4, pt4, porig);
    k_select <<<1, 1024, 0, stream>>>(out_pred, thres);
    k_nn     <<<(4 * NSL) * NSL, 256, 0, stream>>>(tgt4, pt4, porig, cnt, partial);
    k_final  <<<N_PTS / 64, 256, 0, stream>>>(coords, bmask, thres, partial, cnt,
                                              out_pred, out_fea, out_keep, out_kt, out_loss);
}